// Round 8
// baseline (707.427 us; speedup 1.0000x reference)
//
#include <hip/hip_runtime.h>

// GAT 3-layer forward on MI355X — round 8.
// vs round 7: aggregation phase B back to full-wave-per-edge with UNIFORM (scalar-pipe)
// csr loads (R7's per-lane csp[j] chained two VMEM ops -> regression), f16 feat rows
// consumed via packed-half fma (v_fma_mix: no unpack, no 64-bit addr), and EXACT trip
// counts in the last chunk (ELL-16 padding was 43% wasted phase-B work at avg deg 16).

typedef __attribute__((ext_vector_type(8))) short s8v;
typedef __attribute__((ext_vector_type(4))) float f4v;
typedef __attribute__((ext_vector_type(2))) _Float16 h2;
typedef __attribute__((ext_vector_type(4))) _Float16 h4;

__device__ __forceinline__ unsigned short f2bf(float f) {
  unsigned int x = __float_as_uint(f);
  x += 0x7fffu + ((x >> 16) & 1u);          // RTNE
  return (unsigned short)(x >> 16);
}
__device__ __forceinline__ float bf2f(unsigned short u) {
  return __uint_as_float(((unsigned int)u) << 16);
}
__device__ __forceinline__ unsigned short f2h(float f) {
  _Float16 h = (_Float16)f;
  return __builtin_bit_cast(unsigned short, h);
}
__device__ __forceinline__ float lrelu(float x) { return fmaxf(x, 0.2f * x); }
__device__ __forceinline__ float elu1(float x) { return x > 0.f ? x : expm1f(x); }

// ---------------- CSR build (padded to multiples of 16 per node) ----------------
__global__ __launch_bounds__(256) void hist_k(const int* __restrict__ dst, int* __restrict__ counts, int E) {
  int t = blockIdx.x * 256 + threadIdx.x;
  if (t < E) atomicAdd(&counts[dst[t]], 1);
}

__global__ __launch_bounds__(256) void scan1(const int* __restrict__ counts, int* __restrict__ rsp,
                                             int* __restrict__ bsum, int Nn) {
  __shared__ int s[256];
  int t = threadIdx.x;
  int base = blockIdx.x * 1024 + t * 4;
  int v0 = (base + 0 < Nn) ? ((counts[base + 0] + 15) & ~15) : 0;
  int v1 = (base + 1 < Nn) ? ((counts[base + 1] + 15) & ~15) : 0;
  int v2 = (base + 2 < Nn) ? ((counts[base + 2] + 15) & ~15) : 0;
  int v3 = (base + 3 < Nn) ? ((counts[base + 3] + 15) & ~15) : 0;
  s[t] = v0 + v1 + v2 + v3;
  __syncthreads();
  for (int off = 1; off < 256; off <<= 1) {
    int xv = (t >= off) ? s[t - off] : 0;
    __syncthreads();
    s[t] += xv;
    __syncthreads();
  }
  int excl = t ? s[t - 1] : 0;
  if (t == 255) bsum[blockIdx.x] = s[255];
  if (base + 0 < Nn) { rsp[base + 0] = excl; excl += v0; }
  if (base + 1 < Nn) { rsp[base + 1] = excl; excl += v1; }
  if (base + 2 < Nn) { rsp[base + 2] = excl; excl += v2; }
  if (base + 3 < Nn) { rsp[base + 3] = excl; }
}

__global__ __launch_bounds__(128) void scan2(int* __restrict__ bsum, int nb) {
  __shared__ int s[128];
  int t = threadIdx.x;
  s[t] = (t < nb) ? bsum[t] : 0;
  __syncthreads();
  for (int off = 1; off < 128; off <<= 1) {
    int xv = (t >= off) ? s[t - off] : 0;
    __syncthreads();
    s[t] += xv;
    __syncthreads();
  }
  if (t < nb) bsum[t] = t ? s[t - 1] : 0;
}

__global__ __launch_bounds__(256) void scan3(int* __restrict__ rsp, const int* __restrict__ bsum,
                                             int* __restrict__ cursor, int Nn) {
  int t = blockIdx.x * 256 + threadIdx.x;
  if (t < Nn) {
    int v = rsp[t] + bsum[t >> 10];
    rsp[t] = v;
    cursor[t] = v;
  }
}

// XCD-affine scatter: bucket p = blockIdx&7 -> each csr region owned by one XCD L2.
__global__ __launch_bounds__(256) void pscatter_k(const int* __restrict__ src, const int* __restrict__ dst,
                                                  int* __restrict__ cursor, int* __restrict__ csr_src,
                                                  int E, int shift) {
  int p = blockIdx.x & 7;
  int pb = blockIdx.x >> 3;
  int stride = (gridDim.x >> 3) * 256;
  for (int e = pb * 256 + threadIdx.x; e < E; e += stride) {
    int d = dst[e];
    if ((d >> shift) == p) {
      int pos = atomicAdd(&cursor[d], 1);
      csr_src[pos] = src[e];
    }
  }
}

// ---------------- fused weight pack: [W | W@al | W@ar | pad | resW], bf16 hi+lo ----------------
__global__ __launch_bounds__(256) void fill_pack(const float* __restrict__ W, const float* __restrict__ al,
                                                 const float* __restrict__ ar, const float* __restrict__ resW,
                                                 unsigned short* __restrict__ out,
                                                 int K, int M, int BF, int H, int RES0) {
  int t = blockIdx.x * 256 + threadIdx.x;
  if (t >= K * M) return;
  int c = t / K, k = t - c * K;
  float v = 0.f;
  if (c < BF) {
    v = W[k * BF + c];
  } else if (c < BF + H) {
    int h = c - BF;
    float s = 0.f;
    for (int d = 0; d < 32; d++) s += W[k * BF + h * 32 + d] * al[h * 32 + d];
    v = s;
  } else if (c < BF + 2 * H) {
    int h = c - BF - H;
    float s = 0.f;
    for (int d = 0; d < 32; d++) s += W[k * BF + h * 32 + d] * ar[h * 32 + d];
    v = s;
  } else if (c >= RES0) {
    v = resW[k * (M - RES0) + (c - RES0)];
  }
  unsigned short hi = f2bf(v);
  out[c * K + k] = hi;
  out[M * K + c * K + k] = f2bf(v - bf2f(hi));
}

__global__ __launch_bounds__(256) void cast_f2bf_k(const float* __restrict__ x, unsigned short* __restrict__ y, int n) {
  int t = blockIdx.x * 256 + threadIdx.x;
  if (t < n) y[t] = f2bf(x[t]);
}

// ---------------- GEMM: A[N,K](bf16) @ Bt[M,K](bf16 hi+lo); feat table written f16 ----------------
template <int K, int M, int R, int BF, int H, int RES0>
__global__ __launch_bounds__(256) void gemm_bf16(const unsigned short* __restrict__ A,
                                                 const unsigned short* __restrict__ Bt,
                                                 unsigned short* __restrict__ feath,
                                                 float* __restrict__ el, float* __restrict__ er,
                                                 float* __restrict__ res, int nRowTiles) {
  int wv = (int)((blockIdx.x * blockDim.x + threadIdx.x) >> 6);
  int tile0 = wv * R;
  if (tile0 >= nRowTiles) return;
  int lane = threadIdx.x & 63;
  int r = lane & 15, q = lane >> 4;
  s8v afrag[R][K / 32];
#pragma unroll
  for (int rr = 0; rr < R; rr++) {
    const unsigned short* arow = A + (size_t)((tile0 + rr) * 16 + r) * K + q * 8;
#pragma unroll
    for (int kk = 0; kk < K / 32; kk++) afrag[rr][kk] = *(const s8v*)(arow + kk * 32);
  }
#pragma unroll
  for (int ct = 0; ct < M / 16; ct++) {
    const unsigned short* brow = Bt + (size_t)(ct * 16 + r) * K + q * 8;
    s8v bhi[K / 32], blo[K / 32];
#pragma unroll
    for (int kk = 0; kk < K / 32; kk++) {
      bhi[kk] = *(const s8v*)(brow + kk * 32);
      blo[kk] = *(const s8v*)(brow + (size_t)M * K + kk * 32);
    }
    int col = ct * 16 + r;
#pragma unroll
    for (int rr = 0; rr < R; rr++) {
      f4v acc = {0.f, 0.f, 0.f, 0.f};
#pragma unroll
      for (int kk = 0; kk < K / 32; kk++) {
        acc = __builtin_amdgcn_mfma_f32_16x16x32_bf16(afrag[rr][kk], bhi[kk], acc, 0, 0, 0);
        acc = __builtin_amdgcn_mfma_f32_16x16x32_bf16(afrag[rr][kk], blo[kk], acc, 0, 0, 0);
      }
      int row0 = (tile0 + rr) * 16 + q * 4;
#pragma unroll
      for (int i = 0; i < 4; i++) {
        float v = acc[i];
        size_t row = (size_t)(row0 + i);
        if (col < BF) {
          feath[row * BF + col] = f2h(v);
        } else if (col < BF + H) {
          el[row * H + (col - BF)] = v;
        } else if (col < BF + 2 * H) {
          er[row * H + (col - BF - H)] = v;
        } else if (RES0 < M && col >= RES0) {
          res[row * (M - RES0) + (col - RES0)] = v;
        }
      }
    }
  }
}

// ---------------- fused single-pass aggregation H=4 ----------------
// Phase A (slot x head): ex = exp(lrelu(el+er)), validity slot<deg, denom in regs.
// Phase B: full wave per edge, lane owns dims {2l,2l+1} (one 4B f16x2 load, 2 packed
// fma); csr values read on the SCALAR pipe (uniform addr). Full chunks unrolled 16;
// last chunk runs exactly cnt iterations (pads would contribute 0 — skip them).
template <int MODE>
__global__ __launch_bounds__(256) void aggregate4(const unsigned short* __restrict__ feath,
                                                  const float* __restrict__ el4,
                                                  const float* __restrict__ er4,
                                                  const int* __restrict__ csr_src,
                                                  const int* __restrict__ rsp,
                                                  const int* __restrict__ counts,
                                                  const float* __restrict__ res,
                                                  unsigned short* __restrict__ vbf,
                                                  float* __restrict__ rnrm, int Nn) {
  int n = (int)((blockIdx.x * blockDim.x + threadIdx.x) >> 6);
  if (n >= Nn) return;
  int lane = threadIdx.x & 63;
  int start = __builtin_amdgcn_readfirstlane(rsp[n]);
  int deg = __builtin_amdgcn_readfirstlane(counts[n]);
  int chunks = (deg + 15) >> 4;
  int slot = lane >> 2, h = lane & 3;
  float ern = er4[(size_t)n * 4 + h];
  int hl = lane >> 4;                        // head of lane's dims (dims 2l..2l+1)
  unsigned dby = (unsigned)lane << 2;        // byte offset into 256B f16 row
  float a0 = 0.f, a1 = 0.f, dsum = 0.f;
  for (int c = 0; c < chunks; c++) {
    const int* csp = csr_src + start + (c << 4);
    // phase A: one (edge,head) per lane
    int sA = csp[slot];
    float exv = 0.f;
    if (((c << 4) + slot) < deg) {
      float e = el4[(size_t)sA * 4 + h] + ern;
      exv = __expf(fmaxf(e, 0.2f * e));
    }
    dsum += exv;
    // phase B
    int cnt = deg - (c << 4);
    cnt = cnt < 16 ? cnt : 16;
#define A4_EDGE(j)                                                                \
    {                                                                             \
      int sj = csp[j];               /* uniform -> scalar pipe */                 \
      float aw = __shfl(exv, ((j) << 2) | hl);                                    \
      h2 fv = *(const h2*)((const char*)feath + (((unsigned)sj << 8) + dby));     \
      a0 = fmaf((float)fv[0], aw, a0);                                            \
      a1 = fmaf((float)fv[1], aw, a1);                                            \
    }
    if (cnt == 16) {
#pragma unroll
      for (int j = 0; j < 16; j++) A4_EDGE(j)
    } else {
      for (int j = 0; j < cnt; j++) A4_EDGE(j)
    }
#undef A4_EDGE
  }
  // per-head denominator totals: after butterfly, lane l holds head (l&3) total
#pragma unroll
  for (int off = 4; off < 64; off <<= 1) dsum += __shfl_xor(dsum, off);
  float inv = dsum > 0.f ? 1.f / dsum : 0.f;
  float invh = __shfl(inv, hl);
  float v0, v1;
  if (MODE == 1) {
    float2 rr = *(const float2*)(res + (size_t)n * 128 + lane * 2);
    v0 = elu1(elu1(a0 * invh + rr.x));
    v1 = elu1(elu1(a1 * invh + rr.y));
  } else {
    v0 = elu1(a0 * invh);
    v1 = elu1(a1 * invh);
  }
  float ss = v0 * v0 + v1 * v1;
#pragma unroll
  for (int off = 1; off < 64; off <<= 1) ss += __shfl_xor(ss, off);
  float rn = sqrtf(1e-6f + ss);
  float ri = 1.f / rn;
  unsigned int pk = (unsigned int)f2bf(v0 * ri) | ((unsigned int)f2bf(v1 * ri) << 16);
  *(unsigned int*)((char*)vbf + ((size_t)n << 8) + (lane << 2)) = pk;
  if (lane == 0) rnrm[n] = rn;
}

// ---------------- fused single-pass aggregation H=1 (layer 2, f16 feat) ----------------
__global__ __launch_bounds__(256) void aggregate1(const unsigned short* __restrict__ feath,
                                                  const float* __restrict__ el1,
                                                  const float* __restrict__ er1,
                                                  const int* __restrict__ csr_src,
                                                  const int* __restrict__ rsp,
                                                  const int* __restrict__ counts,
                                                  const float* __restrict__ res2,
                                                  float* __restrict__ out2, int Nn) {
  int n = (int)((blockIdx.x * blockDim.x + threadIdx.x) >> 6);
  if (n >= Nn) return;
  int lane = threadIdx.x & 63;
  int start = __builtin_amdgcn_readfirstlane(rsp[n]);
  int deg = __builtin_amdgcn_readfirstlane(counts[n]);
  int chunks = (deg + 15) >> 4;
  int l16 = lane & 15;
  float ern = er1[n];
  int g = lane >> 3;                          // 8 edge groups (2 edges per iteration each)
  unsigned dofs8 = (unsigned)(lane & 7) << 3; // byte offset into 64B f16 row
  f4v acc = {0.f, 0.f, 0.f, 0.f};
  float dsum = 0.f;
  for (int c = 0; c < chunks; c++) {
    const int* csp = csr_src + start + (c << 4);
    int sA = csp[l16];
    float exv = 0.f;
    if (((c << 4) + l16) < deg) exv = __expf(lrelu(el1[sA] + ern));
    dsum += exv;
    int cnt = deg - (c << 4);
    cnt = cnt < 16 ? cnt : 16;
    int tmax = (cnt + 7) >> 3;                // skip the all-pad 8-group
    for (int t = 0; t < tmax; t++) {
      int j = (t << 3) + g;
      int sj = __shfl(sA, j);
      float aw = __shfl(exv, j);
      unsigned off = ((unsigned)sj << 6) + dofs8;
      h4 fv = *(const h4*)((const char*)feath + off);
      acc[0] = fmaf((float)fv[0], aw, acc[0]);
      acc[1] = fmaf((float)fv[1], aw, acc[1]);
      acc[2] = fmaf((float)fv[2], aw, acc[2]);
      acc[3] = fmaf((float)fv[3], aw, acc[3]);
    }
  }
#pragma unroll
  for (int off = 1; off < 16; off <<= 1) dsum += __shfl_xor(dsum, off);
  float inv = dsum > 0.f ? 1.f / dsum : 0.f;
#pragma unroll
  for (int off = 8; off < 64; off <<= 1) {
    acc[0] += __shfl_xor(acc[0], off);
    acc[1] += __shfl_xor(acc[1], off);
    acc[2] += __shfl_xor(acc[2], off);
    acc[3] += __shfl_xor(acc[3], off);
  }
  if (lane < 8) {
    float4 rr = *(const float4*)(res2 + (size_t)n * 32 + (lane << 2));
    float4 o;
    o.x = acc[0] * inv + rr.x;
    o.y = acc[1] * inv + rr.y;
    o.z = acc[2] * inv + rr.z;
    o.w = acc[3] * inv + rr.w;
    *(float4*)(out2 + (size_t)n * 32 + (lane << 2)) = o;
  }
}

// ---------------- PairNorm finish ----------------
__global__ __launch_bounds__(256) void colsum_k(const unsigned short* __restrict__ vbf,
                                                const float* __restrict__ rnrm,
                                                float* __restrict__ colsum, int Nn) {
  __shared__ float ls[256];
  int tid = threadIdx.x;
  int c = tid & 127, rsub = tid >> 7;
  float cs = 0.f;
  for (int r = blockIdx.x * 2 + rsub; r < Nn; r += gridDim.x * 2)
    cs += bf2f(vbf[(size_t)r * 128 + c]) * rnrm[r];
  ls[tid] = cs;
  __syncthreads();
  if (tid < 128) atomicAdd(&colsum[tid], ls[tid] + ls[tid + 128]);
}

__global__ __launch_bounds__(256) void sub_k(const unsigned short* __restrict__ vbf,
                                             const float* __restrict__ colsum,
                                             unsigned short* __restrict__ hbf, int Nn, float invN) {
  int t = blockIdx.x * 256 + threadIdx.x;   // one uint2 (4 cols) per thread
  if (t >= Nn * 32) return;
  int c4 = (t & 31) << 2;
  float4 m = *(const float4*)(colsum + c4);
  uint2 u = ((const uint2*)vbf)[t];
  unsigned int r0 = f2bf(__uint_as_float(u.x << 16) - m.x * invN);
  unsigned int r1 = f2bf(__uint_as_float(u.x & 0xffff0000u) - m.y * invN);
  unsigned int r2 = f2bf(__uint_as_float(u.y << 16) - m.z * invN);
  unsigned int r3 = f2bf(__uint_as_float(u.y & 0xffff0000u) - m.w * invN);
  uint2 o;
  o.x = r0 | (r1 << 16);
  o.y = r2 | (r3 << 16);
  ((uint2*)hbf)[t] = o;
}

// ---------------- final: mean over nodes of out2 ----------------
__global__ __launch_bounds__(256) void final_reduce(const float* __restrict__ out2,
                                                    float* __restrict__ outsum, int Nn) {
  __shared__ float ls[32];
  if (threadIdx.x < 32) ls[threadIdx.x] = 0.f;
  __syncthreads();
  int d = threadIdx.x & 31, rl = threadIdx.x >> 5;
  float acc = 0.f;
  for (int n = blockIdx.x * 8 + rl; n < Nn; n += gridDim.x * 8)
    acc += out2[(size_t)n * 32 + d];
  atomicAdd(&ls[d], acc);
  __syncthreads();
  if (threadIdx.x < 32) atomicAdd(&outsum[threadIdx.x], ls[threadIdx.x]);
}

__global__ void finalize_k(const float* __restrict__ outsum, float* __restrict__ out, float invN) {
  int t = threadIdx.x;
  if (t < 32) out[t] = outsum[t] * invN;
}

// ---------------- launcher ----------------
extern "C" void kernel_launch(void* const* d_in, const int* in_sizes, int n_in,
                              void* d_out, int out_size, void* d_ws, size_t ws_size,
                              hipStream_t stream) {
  const float* x     = (const float*)d_in[0];
  const int*   src   = (const int*)d_in[1];
  const int*   dst   = (const int*)d_in[2];
  const float* W0    = (const float*)d_in[3];
  const float* al0   = (const float*)d_in[4];
  const float* ar0   = (const float*)d_in[5];
  const float* W1    = (const float*)d_in[6];
  const float* al1   = (const float*)d_in[7];
  const float* ar1   = (const float*)d_in[8];
  const float* resW1 = (const float*)d_in[9];
  const float* W2    = (const float*)d_in[10];
  const float* al2   = (const float*)d_in[11];
  const float* ar2   = (const float*)d_in[12];
  const float* resW2 = (const float*)d_in[13];
  const int N = in_sizes[0] / 64;   // 100000
  const int E = in_sizes[1];        // 1600000
  const float invN = 1.f / (float)N;
  const int Emax = E + 15 * N + 1024;   // upper bound on padded slot count + margin
  int shift = 0;
  while (((unsigned)(N - 1) >> shift) > 7u) shift++;   // 8 dst-range buckets

  char* p = (char*)d_ws;
  auto alloc = [&](size_t bytes) { char* r = p; p += (bytes + 255) & ~(size_t)255; return r; };

  // zero-initialized region
  char* zbase = p;
  int*   counts  = (int*)alloc((size_t)4 * N);
  float* colsumA = (float*)alloc(512);
  float* colsumB = (float*)alloc(512);
  float* outsum  = (float*)alloc(128);
  size_t zbytes = (size_t)(p - zbase);

  int* rsp    = (int*)alloc((size_t)4 * N);     // padded row starts
  int* cursor = (int*)alloc((size_t)4 * N);
  int* bsum   = (int*)alloc(512);
  int* csr_src = (int*)alloc((size_t)4 * Emax);     // memset 0: pads -> node 0, alpha 0
  unsigned short* hbf    = (unsigned short*)alloc((size_t)2 * N * 128);
  unsigned short* feath  = (unsigned short*)alloc((size_t)2 * N * 128);
  unsigned short* vbf    = (unsigned short*)alloc((size_t)2 * N * 128);
  unsigned short* w0t = (unsigned short*)alloc((size_t)2 * 2 * 144 * 64);
  unsigned short* w1t = (unsigned short*)alloc((size_t)2 * 2 * 272 * 128);
  unsigned short* w2t = (unsigned short*)alloc((size_t)2 * 2 * 80 * 128);
  float* el4  = (float*)alloc((size_t)16 * N);
  float* er4  = (float*)alloc((size_t)16 * N);
  float* res  = (float*)alloc((size_t)4 * N * 128);  // layer-1 residual [N][128]
  float* rnrm = (float*)alloc((size_t)4 * N);
  float* res2 = res;                                 // layer-2 residual [N][32]
  float* out2 = res + (size_t)N * 32;                // layer-2 output   [N][32]

  hipMemsetAsync(zbase, 0, zbytes, stream);
  hipMemsetAsync(csr_src, 0, (size_t)4 * Emax, stream);

  // CSR build (padded)
  int eb = (E + 255) / 256;
  int nb1024 = (N + 1023) / 1024;
  hist_k<<<eb, 256, 0, stream>>>(dst, counts, E);
  scan1<<<nb1024, 256, 0, stream>>>(counts, rsp, bsum, N);
  scan2<<<1, 128, 0, stream>>>(bsum, nb1024);
  scan3<<<(N + 255) / 256, 256, 0, stream>>>(rsp, bsum, cursor, N);
  pscatter_k<<<1024, 256, 0, stream>>>(src, dst, cursor, csr_src, E, shift);

  // weights: [W | W@al | W@ar | pad | resW] transposed, bf16 hi+lo; input cast
  fill_pack<<<(144 * 64 + 255) / 256, 256, 0, stream>>>(W0, al0, ar0, nullptr, w0t, 64, 144, 128, 4, 144);
  fill_pack<<<(272 * 128 + 255) / 256, 256, 0, stream>>>(W1, al1, ar1, resW1, w1t, 128, 272, 128, 4, 144);
  fill_pack<<<(80 * 128 + 255) / 256, 256, 0, stream>>>(W2, al2, ar2, resW2, w2t, 128, 80, 32, 1, 48);
  cast_f2bf_k<<<(N * 64 + 255) / 256, 256, 0, stream>>>(x, hbf, N * 64);

  const int rowTiles = N / 16;                  // 6250, divisible by R=5
  const int gblocks = (rowTiles / 5 + 3) / 4;   // 1250 waves, 4/block
  const int aggblocks = (N + 3) / 4;            // wave per node

  // Layer 0
  gemm_bf16<64, 144, 5, 128, 4, 144><<<gblocks, 256, 0, stream>>>(hbf, w0t, feath, el4, er4, nullptr, rowTiles);
  aggregate4<0><<<aggblocks, 256, 0, stream>>>(feath, el4, er4, csr_src, rsp, counts, nullptr, vbf, rnrm, N);
  colsum_k<<<512, 256, 0, stream>>>(vbf, rnrm, colsumA, N);
  sub_k<<<(N * 32 + 255) / 256, 256, 0, stream>>>(vbf, colsumA, hbf, N, invN);

  // Layer 1
  gemm_bf16<128, 272, 5, 128, 4, 144><<<gblocks, 256, 0, stream>>>(hbf, w1t, feath, el4, er4, res, rowTiles);
  aggregate4<1><<<aggblocks, 256, 0, stream>>>(feath, el4, er4, csr_src, rsp, counts, res, vbf, rnrm, N);
  colsum_k<<<512, 256, 0, stream>>>(vbf, rnrm, colsumB, N);
  sub_k<<<(N * 32 + 255) / 256, 256, 0, stream>>>(vbf, colsumB, hbf, N, invN);

  // Layer 2
  gemm_bf16<128, 80, 5, 32, 1, 48><<<gblocks, 256, 0, stream>>>(hbf, w2t, feath, el4, er4, res2, rowTiles);
  aggregate1<<<aggblocks, 256, 0, stream>>>(feath, el4, er4, csr_src, rsp, counts, res2, out2, N);
  final_reduce<<<512, 256, 0, stream>>>(out2, outsum, N);
  finalize_k<<<1, 64, 0, stream>>>(outsum, (float*)d_out, invN);
}

// Round 9
// 653.678 us; speedup vs baseline: 1.0822x; 1.0822x over previous
//
#include <hip/hip_runtime.h>

// GAT 3-layer forward on MI355X — round 9.
// Phase B reverted to the measured-best R6 structure: 16 per-lane csp[j] vector loads
// batched up-front (MLP was the property R7/R8 destroyed -> 94/106us regressions),
// fully unrolled 16-edge body, full-chunk padding (no branchy tails). Kept from R7/R8:
// f16 feat table consumed via fma_mix (no unpack VALU) and memset-0 pads (no clamp).

typedef __attribute__((ext_vector_type(8))) short s8v;
typedef __attribute__((ext_vector_type(4))) float f4v;
typedef __attribute__((ext_vector_type(2))) _Float16 h2;
typedef __attribute__((ext_vector_type(4))) _Float16 h4;

__device__ __forceinline__ unsigned short f2bf(float f) {
  unsigned int x = __float_as_uint(f);
  x += 0x7fffu + ((x >> 16) & 1u);          // RTNE
  return (unsigned short)(x >> 16);
}
__device__ __forceinline__ float bf2f(unsigned short u) {
  return __uint_as_float(((unsigned int)u) << 16);
}
__device__ __forceinline__ unsigned short f2h(float f) {
  _Float16 h = (_Float16)f;
  return __builtin_bit_cast(unsigned short, h);
}
__device__ __forceinline__ float lrelu(float x) { return fmaxf(x, 0.2f * x); }
__device__ __forceinline__ float elu1(float x) { return x > 0.f ? x : expm1f(x); }

// ---------------- CSR build (padded to multiples of 16 per node) ----------------
__global__ __launch_bounds__(256) void hist_k(const int* __restrict__ dst, int* __restrict__ counts, int E) {
  int t = blockIdx.x * 256 + threadIdx.x;
  if (t < E) atomicAdd(&counts[dst[t]], 1);
}

__global__ __launch_bounds__(256) void scan1(const int* __restrict__ counts, int* __restrict__ rsp,
                                             int* __restrict__ bsum, int Nn) {
  __shared__ int s[256];
  int t = threadIdx.x;
  int base = blockIdx.x * 1024 + t * 4;
  int v0 = (base + 0 < Nn) ? ((counts[base + 0] + 15) & ~15) : 0;
  int v1 = (base + 1 < Nn) ? ((counts[base + 1] + 15) & ~15) : 0;
  int v2 = (base + 2 < Nn) ? ((counts[base + 2] + 15) & ~15) : 0;
  int v3 = (base + 3 < Nn) ? ((counts[base + 3] + 15) & ~15) : 0;
  s[t] = v0 + v1 + v2 + v3;
  __syncthreads();
  for (int off = 1; off < 256; off <<= 1) {
    int xv = (t >= off) ? s[t - off] : 0;
    __syncthreads();
    s[t] += xv;
    __syncthreads();
  }
  int excl = t ? s[t - 1] : 0;
  if (t == 255) bsum[blockIdx.x] = s[255];
  if (base + 0 < Nn) { rsp[base + 0] = excl; excl += v0; }
  if (base + 1 < Nn) { rsp[base + 1] = excl; excl += v1; }
  if (base + 2 < Nn) { rsp[base + 2] = excl; excl += v2; }
  if (base + 3 < Nn) { rsp[base + 3] = excl; }
}

__global__ __launch_bounds__(128) void scan2(int* __restrict__ bsum, int nb) {
  __shared__ int s[128];
  int t = threadIdx.x;
  s[t] = (t < nb) ? bsum[t] : 0;
  __syncthreads();
  for (int off = 1; off < 128; off <<= 1) {
    int xv = (t >= off) ? s[t - off] : 0;
    __syncthreads();
    s[t] += xv;
    __syncthreads();
  }
  if (t < nb) bsum[t] = t ? s[t - 1] : 0;
}

__global__ __launch_bounds__(256) void scan3(int* __restrict__ rsp, const int* __restrict__ bsum,
                                             int* __restrict__ cursor, int Nn) {
  int t = blockIdx.x * 256 + threadIdx.x;
  if (t < Nn) {
    int v = rsp[t] + bsum[t >> 10];
    rsp[t] = v;
    cursor[t] = v;
  }
}

// XCD-affine scatter: bucket p = blockIdx&7 -> each csr region owned by one XCD L2.
__global__ __launch_bounds__(256) void pscatter_k(const int* __restrict__ src, const int* __restrict__ dst,
                                                  int* __restrict__ cursor, int* __restrict__ csr_src,
                                                  int E, int shift) {
  int p = blockIdx.x & 7;
  int pb = blockIdx.x >> 3;
  int stride = (gridDim.x >> 3) * 256;
  for (int e = pb * 256 + threadIdx.x; e < E; e += stride) {
    int d = dst[e];
    if ((d >> shift) == p) {
      int pos = atomicAdd(&cursor[d], 1);
      csr_src[pos] = src[e];
    }
  }
}

// ---------------- fused weight pack: [W | W@al | W@ar | pad | resW], bf16 hi+lo ----------------
__global__ __launch_bounds__(256) void fill_pack(const float* __restrict__ W, const float* __restrict__ al,
                                                 const float* __restrict__ ar, const float* __restrict__ resW,
                                                 unsigned short* __restrict__ out,
                                                 int K, int M, int BF, int H, int RES0) {
  int t = blockIdx.x * 256 + threadIdx.x;
  if (t >= K * M) return;
  int c = t / K, k = t - c * K;
  float v = 0.f;
  if (c < BF) {
    v = W[k * BF + c];
  } else if (c < BF + H) {
    int h = c - BF;
    float s = 0.f;
    for (int d = 0; d < 32; d++) s += W[k * BF + h * 32 + d] * al[h * 32 + d];
    v = s;
  } else if (c < BF + 2 * H) {
    int h = c - BF - H;
    float s = 0.f;
    for (int d = 0; d < 32; d++) s += W[k * BF + h * 32 + d] * ar[h * 32 + d];
    v = s;
  } else if (c >= RES0) {
    v = resW[k * (M - RES0) + (c - RES0)];
  }
  unsigned short hi = f2bf(v);
  out[c * K + k] = hi;
  out[M * K + c * K + k] = f2bf(v - bf2f(hi));
}

__global__ __launch_bounds__(256) void cast_f2bf_k(const float* __restrict__ x, unsigned short* __restrict__ y, int n) {
  int t = blockIdx.x * 256 + threadIdx.x;
  if (t < n) y[t] = f2bf(x[t]);
}

// ---------------- GEMM: A[N,K](bf16) @ Bt[M,K](bf16 hi+lo); feat table written f16 ----------------
template <int K, int M, int R, int BF, int H, int RES0>
__global__ __launch_bounds__(256) void gemm_bf16(const unsigned short* __restrict__ A,
                                                 const unsigned short* __restrict__ Bt,
                                                 unsigned short* __restrict__ feath,
                                                 float* __restrict__ el, float* __restrict__ er,
                                                 float* __restrict__ res, int nRowTiles) {
  int wv = (int)((blockIdx.x * blockDim.x + threadIdx.x) >> 6);
  int tile0 = wv * R;
  if (tile0 >= nRowTiles) return;
  int lane = threadIdx.x & 63;
  int r = lane & 15, q = lane >> 4;
  s8v afrag[R][K / 32];
#pragma unroll
  for (int rr = 0; rr < R; rr++) {
    const unsigned short* arow = A + (size_t)((tile0 + rr) * 16 + r) * K + q * 8;
#pragma unroll
    for (int kk = 0; kk < K / 32; kk++) afrag[rr][kk] = *(const s8v*)(arow + kk * 32);
  }
#pragma unroll
  for (int ct = 0; ct < M / 16; ct++) {
    const unsigned short* brow = Bt + (size_t)(ct * 16 + r) * K + q * 8;
    s8v bhi[K / 32], blo[K / 32];
#pragma unroll
    for (int kk = 0; kk < K / 32; kk++) {
      bhi[kk] = *(const s8v*)(brow + kk * 32);
      blo[kk] = *(const s8v*)(brow + (size_t)M * K + kk * 32);
    }
    int col = ct * 16 + r;
#pragma unroll
    for (int rr = 0; rr < R; rr++) {
      f4v acc = {0.f, 0.f, 0.f, 0.f};
#pragma unroll
      for (int kk = 0; kk < K / 32; kk++) {
        acc = __builtin_amdgcn_mfma_f32_16x16x32_bf16(afrag[rr][kk], bhi[kk], acc, 0, 0, 0);
        acc = __builtin_amdgcn_mfma_f32_16x16x32_bf16(afrag[rr][kk], blo[kk], acc, 0, 0, 0);
      }
      int row0 = (tile0 + rr) * 16 + q * 4;
#pragma unroll
      for (int i = 0; i < 4; i++) {
        float v = acc[i];
        size_t row = (size_t)(row0 + i);
        if (col < BF) {
          feath[row * BF + col] = f2h(v);
        } else if (col < BF + H) {
          el[row * H + (col - BF)] = v;
        } else if (col < BF + 2 * H) {
          er[row * H + (col - BF - H)] = v;
        } else if (RES0 < M && col >= RES0) {
          res[row * (M - RES0) + (col - RES0)] = v;
        }
      }
    }
  }
}

// ---------------- fused single-pass aggregation H=4 (R6 structure + f16 fma_mix) ----------------
// Phase A (slot x head): ex = exp(lrelu(el+er)), validity slot<deg, denom in regs.
// Phase B: 16 edges/chunk, whole wave per edge, lane owns dims {2l,2l+1}; the 16 csr
// values are fetched as BATCHED per-lane vector loads up-front (max MLP), body fully
// unrolled. Pads are node 0 with aw=0 (memset-0 csr). Normalize at end + epilogue.
template <int MODE>
__global__ __launch_bounds__(256) void aggregate4(const unsigned short* __restrict__ feath,
                                                  const float* __restrict__ el4,
                                                  const float* __restrict__ er4,
                                                  const int* __restrict__ csr_src,
                                                  const int* __restrict__ rsp,
                                                  const int* __restrict__ counts,
                                                  const float* __restrict__ res,
                                                  unsigned short* __restrict__ vbf,
                                                  float* __restrict__ rnrm, int Nn) {
  int n = (int)((blockIdx.x * blockDim.x + threadIdx.x) >> 6);
  if (n >= Nn) return;
  int lane = threadIdx.x & 63;
  int start = __builtin_amdgcn_readfirstlane(rsp[n]);
  int deg = __builtin_amdgcn_readfirstlane(counts[n]);
  int chunks = (deg + 15) >> 4;
  int slot = lane >> 2, h = lane & 3;
  float ern = er4[(size_t)n * 4 + h];
  int hl = lane >> 4;                        // head of lane's dims (dims 2l..2l+1)
  unsigned dby = (unsigned)lane << 2;        // byte offset into 256B f16 row
  float a0 = 0.f, a1 = 0.f, dsum = 0.f;
  for (int c = 0; c < chunks; c++) {
    const int* csp = csr_src + start + (c << 4);
    // phase A: one (edge,head) per lane
    int sA = csp[slot];
    float exv = 0.f;
    if (((c << 4) + slot) < deg) {
      float e = el4[(size_t)sA * 4 + h] + ern;
      exv = __expf(fmaxf(e, 0.2f * e));
    }
    dsum += exv;
    // phase B: batch all 16 csr reads first (independent loads in flight)
    int sj[16];
#pragma unroll
    for (int j = 0; j < 16; j++) sj[j] = csp[j];
#pragma unroll
    for (int j = 0; j < 16; j++) {
      float aw = __shfl(exv, (j << 2) | hl);
      h2 fv = *(const h2*)((const char*)feath + (((unsigned)sj[j] << 8) + dby));
      a0 = fmaf((float)fv[0], aw, a0);
      a1 = fmaf((float)fv[1], aw, a1);
    }
  }
  // per-head denominator totals: after butterfly, lane l holds head (l&3) total
#pragma unroll
  for (int off = 4; off < 64; off <<= 1) dsum += __shfl_xor(dsum, off);
  float inv = dsum > 0.f ? 1.f / dsum : 0.f;
  float invh = __shfl(inv, hl);
  float v0, v1;
  if (MODE == 1) {
    float2 rr = *(const float2*)(res + (size_t)n * 128 + lane * 2);
    v0 = elu1(elu1(a0 * invh + rr.x));
    v1 = elu1(elu1(a1 * invh + rr.y));
  } else {
    v0 = elu1(a0 * invh);
    v1 = elu1(a1 * invh);
  }
  float ss = v0 * v0 + v1 * v1;
#pragma unroll
  for (int off = 1; off < 64; off <<= 1) ss += __shfl_xor(ss, off);
  float rn = sqrtf(1e-6f + ss);
  float ri = 1.f / rn;
  unsigned int pk = (unsigned int)f2bf(v0 * ri) | ((unsigned int)f2bf(v1 * ri) << 16);
  *(unsigned int*)((char*)vbf + ((size_t)n << 8) + (lane << 2)) = pk;
  if (lane == 0) rnrm[n] = rn;
}

// ---------------- fused single-pass aggregation H=1 (layer 2, f16 feat) ----------------
__global__ __launch_bounds__(256) void aggregate1(const unsigned short* __restrict__ feath,
                                                  const float* __restrict__ el1,
                                                  const float* __restrict__ er1,
                                                  const int* __restrict__ csr_src,
                                                  const int* __restrict__ rsp,
                                                  const int* __restrict__ counts,
                                                  const float* __restrict__ res2,
                                                  float* __restrict__ out2, int Nn) {
  int n = (int)((blockIdx.x * blockDim.x + threadIdx.x) >> 6);
  if (n >= Nn) return;
  int lane = threadIdx.x & 63;
  int start = __builtin_amdgcn_readfirstlane(rsp[n]);
  int deg = __builtin_amdgcn_readfirstlane(counts[n]);
  int chunks = (deg + 15) >> 4;
  int l16 = lane & 15;
  float ern = er1[n];
  int g = lane >> 3;                          // 8 edge groups (2 edges each per chunk)
  unsigned dofs8 = (unsigned)(lane & 7) << 3; // byte offset into 64B f16 row
  f4v acc = {0.f, 0.f, 0.f, 0.f};
  float dsum = 0.f;
  for (int c = 0; c < chunks; c++) {
    const int* csp = csr_src + start + (c << 4);
    int sA = csp[l16];
    float exv = 0.f;
    if (((c << 4) + l16) < deg) exv = __expf(lrelu(el1[sA] + ern));
    dsum += exv;
#pragma unroll
    for (int t = 0; t < 2; t++) {
      int j = (t << 3) + g;
      int sj = __shfl(sA, j);
      float aw = __shfl(exv, j);
      h4 fv = *(const h4*)((const char*)feath + (((unsigned)sj << 6) + dofs8));
      acc[0] = fmaf((float)fv[0], aw, acc[0]);
      acc[1] = fmaf((float)fv[1], aw, acc[1]);
      acc[2] = fmaf((float)fv[2], aw, acc[2]);
      acc[3] = fmaf((float)fv[3], aw, acc[3]);
    }
  }
#pragma unroll
  for (int off = 1; off < 16; off <<= 1) dsum += __shfl_xor(dsum, off);
  float inv = dsum > 0.f ? 1.f / dsum : 0.f;
#pragma unroll
  for (int off = 8; off < 64; off <<= 1) {
    acc[0] += __shfl_xor(acc[0], off);
    acc[1] += __shfl_xor(acc[1], off);
    acc[2] += __shfl_xor(acc[2], off);
    acc[3] += __shfl_xor(acc[3], off);
  }
  if (lane < 8) {
    float4 rr = *(const float4*)(res2 + (size_t)n * 32 + (lane << 2));
    float4 o;
    o.x = acc[0] * inv + rr.x;
    o.y = acc[1] * inv + rr.y;
    o.z = acc[2] * inv + rr.z;
    o.w = acc[3] * inv + rr.w;
    *(float4*)(out2 + (size_t)n * 32 + (lane << 2)) = o;
  }
}

// ---------------- PairNorm finish ----------------
__global__ __launch_bounds__(256) void colsum_k(const unsigned short* __restrict__ vbf,
                                                const float* __restrict__ rnrm,
                                                float* __restrict__ colsum, int Nn) {
  __shared__ float ls[256];
  int tid = threadIdx.x;
  int c = tid & 127, rsub = tid >> 7;
  float cs = 0.f;
  for (int r = blockIdx.x * 2 + rsub; r < Nn; r += gridDim.x * 2)
    cs += bf2f(vbf[(size_t)r * 128 + c]) * rnrm[r];
  ls[tid] = cs;
  __syncthreads();
  if (tid < 128) atomicAdd(&colsum[tid], ls[tid] + ls[tid + 128]);
}

__global__ __launch_bounds__(256) void sub_k(const unsigned short* __restrict__ vbf,
                                             const float* __restrict__ colsum,
                                             unsigned short* __restrict__ hbf, int Nn, float invN) {
  int t = blockIdx.x * 256 + threadIdx.x;   // one uint2 (4 cols) per thread
  if (t >= Nn * 32) return;
  int c4 = (t & 31) << 2;
  float4 m = *(const float4*)(colsum + c4);
  uint2 u = ((const uint2*)vbf)[t];
  unsigned int r0 = f2bf(__uint_as_float(u.x << 16) - m.x * invN);
  unsigned int r1 = f2bf(__uint_as_float(u.x & 0xffff0000u) - m.y * invN);
  unsigned int r2 = f2bf(__uint_as_float(u.y << 16) - m.z * invN);
  unsigned int r3 = f2bf(__uint_as_float(u.y & 0xffff0000u) - m.w * invN);
  uint2 o;
  o.x = r0 | (r1 << 16);
  o.y = r2 | (r3 << 16);
  ((uint2*)hbf)[t] = o;
}

// ---------------- final: mean over nodes of out2 ----------------
__global__ __launch_bounds__(256) void final_reduce(const float* __restrict__ out2,
                                                    float* __restrict__ outsum, int Nn) {
  __shared__ float ls[32];
  if (threadIdx.x < 32) ls[threadIdx.x] = 0.f;
  __syncthreads();
  int d = threadIdx.x & 31, rl = threadIdx.x >> 5;
  float acc = 0.f;
  for (int n = blockIdx.x * 8 + rl; n < Nn; n += gridDim.x * 8)
    acc += out2[(size_t)n * 32 + d];
  atomicAdd(&ls[d], acc);
  __syncthreads();
  if (threadIdx.x < 32) atomicAdd(&outsum[threadIdx.x], ls[threadIdx.x]);
}

__global__ void finalize_k(const float* __restrict__ outsum, float* __restrict__ out, float invN) {
  int t = threadIdx.x;
  if (t < 32) out[t] = outsum[t] * invN;
}

// ---------------- launcher ----------------
extern "C" void kernel_launch(void* const* d_in, const int* in_sizes, int n_in,
                              void* d_out, int out_size, void* d_ws, size_t ws_size,
                              hipStream_t stream) {
  const float* x     = (const float*)d_in[0];
  const int*   src   = (const int*)d_in[1];
  const int*   dst   = (const int*)d_in[2];
  const float* W0    = (const float*)d_in[3];
  const float* al0   = (const float*)d_in[4];
  const float* ar0   = (const float*)d_in[5];
  const float* W1    = (const float*)d_in[6];
  const float* al1   = (const float*)d_in[7];
  const float* ar1   = (const float*)d_in[8];
  const float* resW1 = (const float*)d_in[9];
  const float* W2    = (const float*)d_in[10];
  const float* al2   = (const float*)d_in[11];
  const float* ar2   = (const float*)d_in[12];
  const float* resW2 = (const float*)d_in[13];
  const int N = in_sizes[0] / 64;   // 100000
  const int E = in_sizes[1];        // 1600000
  const float invN = 1.f / (float)N;
  const int Emax = E + 15 * N + 1024;   // upper bound on padded slot count + margin
  int shift = 0;
  while (((unsigned)(N - 1) >> shift) > 7u) shift++;   // 8 dst-range buckets

  char* p = (char*)d_ws;
  auto alloc = [&](size_t bytes) { char* r = p; p += (bytes + 255) & ~(size_t)255; return r; };

  // zero-initialized region
  char* zbase = p;
  int*   counts  = (int*)alloc((size_t)4 * N);
  float* colsumA = (float*)alloc(512);
  float* colsumB = (float*)alloc(512);
  float* outsum  = (float*)alloc(128);
  size_t zbytes = (size_t)(p - zbase);

  int* rsp    = (int*)alloc((size_t)4 * N);     // padded row starts
  int* cursor = (int*)alloc((size_t)4 * N);
  int* bsum   = (int*)alloc(512);
  int* csr_src = (int*)alloc((size_t)4 * Emax);     // memset 0: pads -> node 0, alpha 0
  unsigned short* hbf    = (unsigned short*)alloc((size_t)2 * N * 128);
  unsigned short* feath  = (unsigned short*)alloc((size_t)2 * N * 128);
  unsigned short* vbf    = (unsigned short*)alloc((size_t)2 * N * 128);
  unsigned short* w0t = (unsigned short*)alloc((size_t)2 * 2 * 144 * 64);
  unsigned short* w1t = (unsigned short*)alloc((size_t)2 * 2 * 272 * 128);
  unsigned short* w2t = (unsigned short*)alloc((size_t)2 * 2 * 80 * 128);
  float* el4  = (float*)alloc((size_t)16 * N);
  float* er4  = (float*)alloc((size_t)16 * N);
  float* res  = (float*)alloc((size_t)4 * N * 128);  // layer-1 residual [N][128]
  float* rnrm = (float*)alloc((size_t)4 * N);
  float* res2 = res;                                 // layer-2 residual [N][32]
  float* out2 = res + (size_t)N * 32;                // layer-2 output   [N][32]

  hipMemsetAsync(zbase, 0, zbytes, stream);
  hipMemsetAsync(csr_src, 0, (size_t)4 * Emax, stream);

  // CSR build (padded)
  int eb = (E + 255) / 256;
  int nb1024 = (N + 1023) / 1024;
  hist_k<<<eb, 256, 0, stream>>>(dst, counts, E);
  scan1<<<nb1024, 256, 0, stream>>>(counts, rsp, bsum, N);
  scan2<<<1, 128, 0, stream>>>(bsum, nb1024);
  scan3<<<(N + 255) / 256, 256, 0, stream>>>(rsp, bsum, cursor, N);
  pscatter_k<<<1024, 256, 0, stream>>>(src, dst, cursor, csr_src, E, shift);

  // weights: [W | W@al | W@ar | pad | resW] transposed, bf16 hi+lo; input cast
  fill_pack<<<(144 * 64 + 255) / 256, 256, 0, stream>>>(W0, al0, ar0, nullptr, w0t, 64, 144, 128, 4, 144);
  fill_pack<<<(272 * 128 + 255) / 256, 256, 0, stream>>>(W1, al1, ar1, resW1, w1t, 128, 272, 128, 4, 144);
  fill_pack<<<(80 * 128 + 255) / 256, 256, 0, stream>>>(W2, al2, ar2, resW2, w2t, 128, 80, 32, 1, 48);
  cast_f2bf_k<<<(N * 64 + 255) / 256, 256, 0, stream>>>(x, hbf, N * 64);

  const int rowTiles = N / 16;                  // 6250, divisible by R=5
  const int gblocks = (rowTiles / 5 + 3) / 4;   // 1250 waves, 4/block
  const int aggblocks = (N + 3) / 4;            // wave per node

  // Layer 0
  gemm_bf16<64, 144, 5, 128, 4, 144><<<gblocks, 256, 0, stream>>>(hbf, w0t, feath, el4, er4, nullptr, rowTiles);
  aggregate4<0><<<aggblocks, 256, 0, stream>>>(feath, el4, er4, csr_src, rsp, counts, nullptr, vbf, rnrm, N);
  colsum_k<<<512, 256, 0, stream>>>(vbf, rnrm, colsumA, N);
  sub_k<<<(N * 32 + 255) / 256, 256, 0, stream>>>(vbf, colsumA, hbf, N, invN);

  // Layer 1
  gemm_bf16<128, 272, 5, 128, 4, 144><<<gblocks, 256, 0, stream>>>(hbf, w1t, feath, el4, er4, res, rowTiles);
  aggregate4<1><<<aggblocks, 256, 0, stream>>>(feath, el4, er4, csr_src, rsp, counts, res, vbf, rnrm, N);
  colsum_k<<<512, 256, 0, stream>>>(vbf, rnrm, colsumB, N);
  sub_k<<<(N * 32 + 255) / 256, 256, 0, stream>>>(vbf, colsumB, hbf, N, invN);

  // Layer 2
  gemm_bf16<128, 80, 5, 32, 1, 48><<<gblocks, 256, 0, stream>>>(hbf, w2t, feath, el4, er4, res2, rowTiles);
  aggregate1<<<aggblocks, 256, 0, stream>>>(feath, el4, er4, csr_src, rsp, counts, res2, out2, N);
  final_reduce<<<512, 256, 0, stream>>>(out2, outsum, N);
  finalize_k<<<1, 64, 0, stream>>>(outsum, (float*)d_out, invN);
}